// Round 1
// baseline (464.651 us; speedup 1.0000x reference)
//
#include <hip/hip_runtime.h>
#include <hip/hip_bf16.h>

#define DD 300
#define SS 512
#define NWAVE 8

// ---------------------------------------------------------------------------
// Kernel A: precompute folded vectors/scalars into workspace
//   ws[0]        = c_k = dot(bk, wk)
//   ws[1]        = c_q = dot(bq, wq)
//   ws[16..316)  = u   = wk @ Wk      (k_score projection)
//   ws[320..620) = uq  = wq @ Wq      (query-scalar projection)
//   ws[640..940) = bc  = Wp @ bk + bp
//   ws[1024..)   = Wc  = Wp @ Wk      (fused out-projection, filled by kernel B)
// ---------------------------------------------------------------------------
__global__ void precompute_vec(const float* __restrict__ Wk, const float* __restrict__ bk,
                               const float* __restrict__ Wq, const float* __restrict__ bq,
                               const float* __restrict__ w_mlp,
                               const float* __restrict__ Wp, const float* __restrict__ bp,
                               float* __restrict__ ws)
{
    const int tid = threadIdx.x;           // 320 threads
    const float* wkv = w_mlp;              // w_mlp[0:300]
    const float* wqv = w_mlp + DD;         // w_mlp[300:600]
    if (tid < DD) {
        float u = 0.f, uq = 0.f, bc = 0.f;
        for (int e = 0; e < DD; ++e) {
            u  += wkv[e] * Wk[e * DD + tid];   // column reads, coalesced across tid
            uq += wqv[e] * Wq[e * DD + tid];
            bc += Wp[tid * DD + e] * bk[e];
        }
        ws[16 + tid]  = u;
        ws[320 + tid] = uq;
        ws[640 + tid] = bc + bp[tid];
    }
    if (tid == 0) {
        float ck = 0.f, cq = 0.f;
        for (int e = 0; e < DD; ++e) { ck += bk[e] * wkv[e]; cq += bq[e] * wqv[e]; }
        ws[0] = ck;
        ws[1] = cq;
    }
}

// ---------------------------------------------------------------------------
// Kernel B: Wc = Wp @ Wk   (300x300 @ 300x300, trivial FLOPs, L2-resident)
// one block per output row i; threads over output column d
// ---------------------------------------------------------------------------
__global__ void precompute_Wc(const float* __restrict__ Wp, const float* __restrict__ Wk,
                              float* __restrict__ Wc)
{
    const int i = blockIdx.x;              // 300 blocks
    const int tid = threadIdx.x;           // 320 threads
    if (tid >= DD) return;
    const float* wpr = Wp + i * DD;
    float a = 0.f;
    for (int e = 0; e < DD; ++e)
        a += wpr[e] * Wk[e * DD + tid];    // Wk column-iter, coalesced across tid
    Wc[i * DD + tid] = a;
}

// ---------------------------------------------------------------------------
// Kernel C: full per-batch-row MemNet. One block per b. 512 threads = 8 waves.
// ---------------------------------------------------------------------------
__global__ __launch_bounds__(512) void memnet_main(
    const int* __restrict__ text, const int* __restrict__ asp,
    const float* __restrict__ emb,
    const float* __restrict__ Wx, const float* __restrict__ bx,
    const float* __restrict__ Wd, const float* __restrict__ bd,
    const float* __restrict__ ws,
    float* __restrict__ out)
{
    const int b    = blockIdx.x;
    const int tid  = threadIdx.x;
    const int wv   = tid >> 6;
    const int lane = tid & 63;

    __shared__ float ks[SS];        // k_score per position
    __shared__ float cw[SS];        // attn-coef = p[s] * w[s] per hop
    __shared__ float wgt[SS];       // position weight w[b,s]
    __shared__ int   ti[SS];        // token ids
    __shared__ float xv[DD];        // current x
    __shared__ float xn[DD];        // x after Wx
    __shared__ float mv[DD];        // attn-weighted memory sum
    __shared__ float u_s[DD];
    __shared__ float uq_s[DD];
    __shared__ float mpart[NWAVE][DD];
    __shared__ float red[NWAVE];
    __shared__ float scal[4];       // [0]=n_asp, [1]=qs, [2]=sumP
    __shared__ int   ilen;

    // ---- load token row, count length via ballot ----
    const int t = text[(size_t)b * SS + tid];
    ti[tid] = t;
    const unsigned long long bal = __ballot(t != 0);
    if (lane == 0) red[wv] = (float)__popcll(bal);
    __syncthreads();
    if (tid == 0) {
        int L = 0;
        for (int w = 0; w < NWAVE; ++w) L += (int)red[w];
        ilen = L;
        int na = 0;
        for (int a = 0; a < 8; ++a) na += (asp[b * 8 + a] != 0);
        scal[0] = (float)na;
    }
    __syncthreads();

    const int   len  = ilen;
    const float lenf = (float)len;
    {
        const int j = tid - (SS - len);
        wgt[tid] = (j >= 0) ? (1.0f - (float)j / lenf) : 1.0f;
    }

    // ---- load folded vectors; compute aspect mean -> xv ----
    if (tid < DD) {
        u_s[tid]  = ws[16 + tid];
        uq_s[tid] = ws[320 + tid];
        float a = 0.f;
        for (int k = 0; k < 8; ++k) {
            const int idx = asp[b * 8 + k];       // emb[0] == 0, safe to include
            a += emb[(size_t)idx * DD + tid];
        }
        xv[tid] = a / scal[0];
    }
    const float c_k = ws[0];
    const float c_q = ws[1];
    __syncthreads();

    // ---- k_score[s] = w[s] * dot(emb[t[s]], u) + c_k  (wave per s) ----
    for (int s = wv; s < SS; s += NWAVE) {
        const int row = ti[s];                     // wave-uniform (from LDS)
        if (row == 0) { if (lane == 0) ks[s] = c_k; continue; }
        const float* er = emb + (size_t)row * DD;
        float a = er[lane]        * u_s[lane]
                + er[lane + 64]   * u_s[lane + 64]
                + er[lane + 128]  * u_s[lane + 128]
                + er[lane + 192]  * u_s[lane + 192];
        if (lane < DD - 256) a += er[lane + 256] * u_s[lane + 256];
        #pragma unroll
        for (int off = 32; off; off >>= 1) a += __shfl_xor(a, off);
        if (lane == 0) ks[s] = wgt[s] * a + c_k;
    }
    __syncthreads();

    // ---- hop loop ----
    for (int hop = 0; hop < 3; ++hop) {
        // xn = Wx @ xv + bx   (wave per output row)
        for (int i = wv; i < DD; i += NWAVE) {
            const float* wr = Wx + i * DD;
            float a = wr[lane]       * xv[lane]
                    + wr[lane + 64]  * xv[lane + 64]
                    + wr[lane + 128] * xv[lane + 128]
                    + wr[lane + 192] * xv[lane + 192];
            if (lane < DD - 256) a += wr[lane + 256] * xv[lane + 256];
            #pragma unroll
            for (int off = 32; off; off >>= 1) a += __shfl_xor(a, off);
            if (lane == 0) xn[i] = a + bx[i];
        }
        __syncthreads();

        // qs = dot(xn, uq) + c_q   (block reduce)
        float pv = (tid < DD) ? xn[tid] * uq_s[tid] : 0.0f;
        #pragma unroll
        for (int off = 32; off; off >>= 1) pv += __shfl_xor(pv, off);
        if (lane == 0) red[wv] = pv;
        __syncthreads();
        if (tid == 0) {
            float s = 0.f;
            for (int w = 0; w < NWAVE; ++w) s += red[w];
            scal[1] = s + c_q;
        }
        __syncthreads();
        const float qs = scal[1];

        // p[s] = exp(tanh(ks+qs));  cw[s] = p*w;  sumP (tanh in (-1,1): exp safe)
        const float p = expf(tanhf(ks[tid] + qs));
        cw[tid] = p * wgt[tid];
        float sp = p;
        #pragma unroll
        for (int off = 32; off; off >>= 1) sp += __shfl_xor(sp, off);
        if (lane == 0) red[wv] = sp;
        __syncthreads();
        if (tid == 0) {
            float s = 0.f;
            for (int w = 0; w < NWAVE; ++w) s += red[w];
            scal[2] = s;
        }
        __syncthreads();
        const float sumP = scal[2];

        // m = sum_s cw[s] * emb[t[s]]  (per-wave register partials over s)
        float a0 = 0.f, a1 = 0.f, a2 = 0.f, a3 = 0.f, a4 = 0.f;
        for (int s = wv; s < SS; s += NWAVE) {
            const int row = ti[s];
            if (row == 0) continue;                // zero row, skip loads
            const float c = cw[s];
            const float* er = emb + (size_t)row * DD;
            a0 += c * er[lane];
            a1 += c * er[lane + 64];
            a2 += c * er[lane + 128];
            a3 += c * er[lane + 192];
            if (lane < DD - 256) a4 += c * er[lane + 256];
        }
        mpart[wv][lane]       = a0;
        mpart[wv][lane + 64]  = a1;
        mpart[wv][lane + 128] = a2;
        mpart[wv][lane + 192] = a3;
        if (lane < DD - 256) mpart[wv][lane + 256] = a4;
        __syncthreads();
        if (tid < DD) {
            float mm = 0.f;
            #pragma unroll
            for (int w = 0; w < NWAVE; ++w) mm += mpart[w][tid];
            mv[tid] = mm / sumP;                   // softmax normalization folded here
        }
        __syncthreads();

        // xv = Wc @ mv + bc + xn
        const float* Wc = ws + 1024;
        const float* bc = ws + 640;
        for (int i = wv; i < DD; i += NWAVE) {
            const float* wr = Wc + i * DD;
            float a = wr[lane]       * mv[lane]
                    + wr[lane + 64]  * mv[lane + 64]
                    + wr[lane + 128] * mv[lane + 128]
                    + wr[lane + 192] * mv[lane + 192];
            if (lane < DD - 256) a += wr[lane + 256] * mv[lane + 256];
            #pragma unroll
            for (int off = 32; off; off >>= 1) a += __shfl_xor(a, off);
            if (lane == 0) xv[i] = a + bc[i] + xn[i];
        }
        __syncthreads();
    }

    // ---- final: out[b,p] = dot(Wd[p], xv) + bd[p], P=3 (wave p) ----
    if (wv < 3) {
        const float* wr = Wd + wv * DD;
        float a = wr[lane]       * xv[lane]
                + wr[lane + 64]  * xv[lane + 64]
                + wr[lane + 128] * xv[lane + 128]
                + wr[lane + 192] * xv[lane + 192];
        if (lane < DD - 256) a += wr[lane + 256] * xv[lane + 256];
        #pragma unroll
        for (int off = 32; off; off >>= 1) a += __shfl_xor(a, off);
        if (lane == 0) out[b * 3 + wv] = a + bd[wv];
    }
}

extern "C" void kernel_launch(void* const* d_in, const int* in_sizes, int n_in,
                              void* d_out, int out_size, void* d_ws, size_t ws_size,
                              hipStream_t stream)
{
    const int*   text = (const int*)d_in[0];
    const int*   asp  = (const int*)d_in[1];
    const float* emb  = (const float*)d_in[2];
    const float* Wx   = (const float*)d_in[3];
    const float* bx   = (const float*)d_in[4];
    const float* Wk   = (const float*)d_in[5];
    const float* bk   = (const float*)d_in[6];
    const float* Wq   = (const float*)d_in[7];
    const float* bq   = (const float*)d_in[8];
    const float* wm   = (const float*)d_in[9];
    const float* Wp   = (const float*)d_in[10];
    const float* bp   = (const float*)d_in[11];
    const float* Wd   = (const float*)d_in[12];
    const float* bd   = (const float*)d_in[13];
    float* out = (float*)d_out;
    float* ws  = (float*)d_ws;

    precompute_vec<<<1, 320, 0, stream>>>(Wk, bk, Wq, bq, wm, Wp, bp, ws);
    precompute_Wc<<<300, 320, 0, stream>>>(Wp, Wk, ws + 1024);
    memnet_main<<<512, 512, 0, stream>>>(text, asp, emb, Wx, bx, Wd, bd, ws, out);
}

// Round 2
// 301.595 us; speedup vs baseline: 1.5406x; 1.5406x over previous
//
#include <hip/hip_runtime.h>
#include <hip/hip_bf16.h>

#define DD 300
#define SS 512
#define NW 16   // waves per block in main kernel

// ---------------------------------------------------------------------------
// Workspace layout (floats):
//   ws[0]        = c_k = dot(bk, wk)
//   ws[1]        = c_q = dot(bq, wq)
//   ws[16..316)  = u   = wk @ Wk
//   ws[320..620) = uq  = wq @ Wq
//   ws[640..940) = bc  = Wp @ bk + bp
//   ws[1024..)   = Wc  = Wp @ Wk   (300x300)
// ---------------------------------------------------------------------------

// One block per output row i (300 blocks, 320 threads = 5 waves).
// Block i: Wc[i,:] (coalesced), u[i], uq[i], bc[i] (block reductions).
// Block 0 additionally: c_k, c_q.
__global__ __launch_bounds__(320) void precompute_all(
    const float* __restrict__ Wk, const float* __restrict__ bk,
    const float* __restrict__ Wq, const float* __restrict__ bq,
    const float* __restrict__ w_mlp,
    const float* __restrict__ Wp, const float* __restrict__ bp,
    float* __restrict__ ws)
{
    const int i    = blockIdx.x;
    const int tid  = threadIdx.x;
    const int wv   = tid >> 6;
    const int lane = tid & 63;
    __shared__ float r1[5], r2[5], r3[5];

    // --- Wc row i: acc over e of Wp[i,e] * Wk[e, tid], 4-way unrolled ---
    if (tid < DD) {
        const float* wpr = Wp + i * DD;
        float a0 = 0.f, a1 = 0.f, a2 = 0.f, a3 = 0.f;
        for (int e = 0; e < DD; e += 4) {
            a0 += wpr[e]     * Wk[(e)     * DD + tid];
            a1 += wpr[e + 1] * Wk[(e + 1) * DD + tid];
            a2 += wpr[e + 2] * Wk[(e + 2) * DD + tid];
            a3 += wpr[e + 3] * Wk[(e + 3) * DD + tid];
        }
        ws[1024 + i * DD + tid] = (a0 + a1) + (a2 + a3);
    }

    // --- u[i], uq[i], bc[i]: one element per thread, block reduce ---
    float p1 = 0.f, p2 = 0.f, p3 = 0.f;
    if (tid < DD) {
        p1 = w_mlp[tid]      * Wk[tid * DD + i];
        p2 = w_mlp[DD + tid] * Wq[tid * DD + i];
        p3 = Wp[i * DD + tid] * bk[tid];
    }
    #pragma unroll
    for (int off = 32; off; off >>= 1) {
        p1 += __shfl_xor(p1, off);
        p2 += __shfl_xor(p2, off);
        p3 += __shfl_xor(p3, off);
    }
    if (lane == 0) { r1[wv] = p1; r2[wv] = p2; r3[wv] = p3; }
    __syncthreads();
    if (tid == 0) {
        float s1 = 0.f, s2 = 0.f, s3 = 0.f;
        for (int w = 0; w < 5; ++w) { s1 += r1[w]; s2 += r2[w]; s3 += r3[w]; }
        ws[16 + i]  = s1;
        ws[320 + i] = s2;
        ws[640 + i] = s3 + bp[i];
    }

    // --- block 0: c_k, c_q ---
    if (i == 0) {
        __syncthreads();
        float q1 = (tid < DD) ? bk[tid] * w_mlp[tid]      : 0.f;
        float q2 = (tid < DD) ? bq[tid] * w_mlp[DD + tid] : 0.f;
        #pragma unroll
        for (int off = 32; off; off >>= 1) {
            q1 += __shfl_xor(q1, off);
            q2 += __shfl_xor(q2, off);
        }
        if (lane == 0) { r1[wv] = q1; r2[wv] = q2; }
        __syncthreads();
        if (tid == 0) {
            float s1 = 0.f, s2 = 0.f;
            for (int w = 0; w < 5; ++w) { s1 += r1[w]; s2 += r2[w]; }
            ws[0] = s1;
            ws[1] = s2;
        }
    }
}

// ---------------------------------------------------------------------------
// Main kernel: one block per batch row. 1024 threads = 16 waves.
// 512 blocks x 16 waves = 32 waves/CU cap (100% occupancy).
// All 300-float row accesses as float4: lane handles f4[lane], lanes<11 also
// f4[64+lane] (75 float4 per row).
// ---------------------------------------------------------------------------
__global__ __launch_bounds__(1024, 8) void memnet_main(
    const int* __restrict__ text, const int* __restrict__ asp,
    const float* __restrict__ emb,
    const float* __restrict__ Wx, const float* __restrict__ bx,
    const float* __restrict__ Wd, const float* __restrict__ bd,
    const float* __restrict__ ws,
    float* __restrict__ out)
{
    const int b    = blockIdx.x;
    const int tid  = threadIdx.x;
    const int wv   = tid >> 6;
    const int lane = tid & 63;

    __shared__ __align__(16) float ks[SS];
    __shared__ __align__(16) float cw[SS];
    __shared__ __align__(16) float wgt[SS];
    __shared__ __align__(16) int   ti[SS];
    __shared__ __align__(16) float xv[DD];
    __shared__ __align__(16) float xn[DD];
    __shared__ __align__(16) float mv[DD];
    __shared__ __align__(16) float u_s[DD];
    __shared__ __align__(16) float uq_s[DD];
    __shared__ __align__(16) float mpart[NW][DD];
    __shared__ float red[NW];
    __shared__ float scal[4];   // [0]=n_asp, [1]=qs, [2]=sumP
    __shared__ int   ilen;

    // ---- token row + length (ballot over waves 0..7) ----
    int t = 0;
    if (tid < SS) { t = text[(size_t)b * SS + tid]; ti[tid] = t; }
    const unsigned long long bal = __ballot(tid < SS && t != 0);
    if (lane == 0) red[wv] = (float)__popcll(bal);
    __syncthreads();
    if (tid == 0) {
        int L = 0;
        for (int w = 0; w < NW; ++w) L += (int)red[w];
        ilen = L;
        int na = 0;
        for (int a = 0; a < 8; ++a) na += (asp[b * 8 + a] != 0);
        scal[0] = (float)na;
    }
    __syncthreads();

    const int   len  = ilen;
    const float lenf = (float)len;
    if (tid < SS) {
        const int j = tid - (SS - len);
        wgt[tid] = (j >= 0) ? (1.0f - (float)j / lenf) : 1.0f;
    }

    // ---- folded vectors + aspect mean ----
    if (tid < DD) {
        u_s[tid]  = ws[16 + tid];
        uq_s[tid] = ws[320 + tid];
        float a = 0.f;
        #pragma unroll
        for (int k = 0; k < 8; ++k) {
            const int idx = asp[b * 8 + k];       // emb[0]==0, safe
            a += emb[(size_t)idx * DD + tid];
        }
        xv[tid] = a / scal[0];
    }
    const float c_k = ws[0];
    const float c_q = ws[1];
    __syncthreads();

    // ---- k_score[s] = wgt[s]*dot(emb[t[s]], u) + c_k  (wave per s) ----
    {
        const float4* u4 = (const float4*)u_s;
        const float4  q0 = u4[lane];
        const float4  q1 = (lane < 11) ? u4[64 + lane] : float4{0, 0, 0, 0};
        #pragma unroll 2
        for (int s = wv; s < SS; s += NW) {
            const int row = ti[s];
            if (row == 0) { if (lane == 0) ks[s] = c_k; continue; }
            const float4* er = (const float4*)(emb + (size_t)row * DD);
            const float4 e0 = er[lane];
            float a = e0.x * q0.x + e0.y * q0.y + e0.z * q0.z + e0.w * q0.w;
            if (lane < 11) {
                const float4 e1 = er[64 + lane];
                a += e1.x * q1.x + e1.y * q1.y + e1.z * q1.z + e1.w * q1.w;
            }
            #pragma unroll
            for (int off = 32; off; off >>= 1) a += __shfl_xor(a, off);
            if (lane == 0) ks[s] = wgt[s] * a + c_k;
        }
    }
    __syncthreads();

    // ---- hop loop ----
    for (int hop = 0; hop < 3; ++hop) {
        // xn = Wx @ xv + bx
        {
            const float4* x4 = (const float4*)xv;
            const float4  v0 = x4[lane];
            const float4  v1 = (lane < 11) ? x4[64 + lane] : float4{0, 0, 0, 0};
            for (int i = wv; i < DD; i += NW) {
                const float4* wr = (const float4*)(Wx + i * DD);
                const float4 w0 = wr[lane];
                float a = w0.x * v0.x + w0.y * v0.y + w0.z * v0.z + w0.w * v0.w;
                if (lane < 11) {
                    const float4 w1 = wr[64 + lane];
                    a += w1.x * v1.x + w1.y * v1.y + w1.z * v1.z + w1.w * v1.w;
                }
                #pragma unroll
                for (int off = 32; off; off >>= 1) a += __shfl_xor(a, off);
                if (lane == 0) xn[i] = a + bx[i];
            }
        }
        __syncthreads();

        // qs = dot(xn, uq) + c_q
        float pv = (tid < DD) ? xn[tid] * uq_s[tid] : 0.0f;
        #pragma unroll
        for (int off = 32; off; off >>= 1) pv += __shfl_xor(pv, off);
        if (lane == 0) red[wv] = pv;
        __syncthreads();
        if (tid == 0) {
            float s = 0.f;
            for (int w = 0; w < NW; ++w) s += red[w];
            scal[1] = s + c_q;
        }
        __syncthreads();
        const float qs = scal[1];

        // p = exp(tanh(ks+qs)); cw = p*wgt; sumP
        float p = 0.f;
        if (tid < SS) {
            p = expf(tanhf(ks[tid] + qs));
            cw[tid] = p * wgt[tid];
        }
        float sp = p;
        #pragma unroll
        for (int off = 32; off; off >>= 1) sp += __shfl_xor(sp, off);
        if (lane == 0) red[wv] = sp;
        __syncthreads();
        if (tid == 0) {
            float s = 0.f;
            for (int w = 0; w < NW; ++w) s += red[w];
            scal[2] = s;
        }
        __syncthreads();
        const float sumP = scal[2];

        // m = sum_s cw[s] * emb[t[s]]  (per-wave float4 register partials)
        {
            float4 acc  = {0, 0, 0, 0};
            float4 accb = {0, 0, 0, 0};
            #pragma unroll 2
            for (int s = wv; s < SS; s += NW) {
                const int row = ti[s];
                if (row == 0) continue;
                const float c = cw[s];
                const float4* er = (const float4*)(emb + (size_t)row * DD);
                const float4 e0 = er[lane];
                acc.x += c * e0.x; acc.y += c * e0.y;
                acc.z += c * e0.z; acc.w += c * e0.w;
                if (lane < 11) {
                    const float4 e1 = er[64 + lane];
                    accb.x += c * e1.x; accb.y += c * e1.y;
                    accb.z += c * e1.z; accb.w += c * e1.w;
                }
            }
            ((float4*)&mpart[wv][0])[lane] = acc;
            if (lane < 11) ((float4*)&mpart[wv][0])[64 + lane] = accb;
        }
        __syncthreads();
        if (tid < DD) {
            float mm = 0.f;
            #pragma unroll
            for (int w = 0; w < NW; ++w) mm += mpart[w][tid];
            mv[tid] = mm / sumP;      // softmax normalization folded in
        }
        __syncthreads();

        // xv = Wc @ mv + bc + xn
        {
            const float* Wc = ws + 1024;
            const float* bc = ws + 640;
            const float4* m4 = (const float4*)mv;
            const float4  v0 = m4[lane];
            const float4  v1 = (lane < 11) ? m4[64 + lane] : float4{0, 0, 0, 0};
            for (int i = wv; i < DD; i += NW) {
                const float4* wr = (const float4*)(Wc + i * DD);
                const float4 w0 = wr[lane];
                float a = w0.x * v0.x + w0.y * v0.y + w0.z * v0.z + w0.w * v0.w;
                if (lane < 11) {
                    const float4 w1 = wr[64 + lane];
                    a += w1.x * v1.x + w1.y * v1.y + w1.z * v1.z + w1.w * v1.w;
                }
                #pragma unroll
                for (int off = 32; off; off >>= 1) a += __shfl_xor(a, off);
                if (lane == 0) xv[i] = a + bc[i] + xn[i];
            }
        }
        __syncthreads();
    }

    // ---- out[b,p] = dot(Wd[p], xv) + bd[p], P=3 ----
    if (wv < 3) {
        const float4* wr = (const float4*)(Wd + wv * DD);
        const float4* x4 = (const float4*)xv;
        const float4 w0 = wr[lane];
        const float4 v0 = x4[lane];
        float a = w0.x * v0.x + w0.y * v0.y + w0.z * v0.z + w0.w * v0.w;
        if (lane < 11) {
            const float4 w1 = wr[64 + lane];
            const float4 v1 = x4[64 + lane];
            a += w1.x * v1.x + w1.y * v1.y + w1.z * v1.z + w1.w * v1.w;
        }
        #pragma unroll
        for (int off = 32; off; off >>= 1) a += __shfl_xor(a, off);
        if (lane == 0) out[b * 3 + wv] = a + bd[wv];
    }
}

extern "C" void kernel_launch(void* const* d_in, const int* in_sizes, int n_in,
                              void* d_out, int out_size, void* d_ws, size_t ws_size,
                              hipStream_t stream)
{
    const int*   text = (const int*)d_in[0];
    const int*   asp  = (const int*)d_in[1];
    const float* emb  = (const float*)d_in[2];
    const float* Wx   = (const float*)d_in[3];
    const float* bx   = (const float*)d_in[4];
    const float* Wk   = (const float*)d_in[5];
    const float* bk   = (const float*)d_in[6];
    const float* Wq   = (const float*)d_in[7];
    const float* bq   = (const float*)d_in[8];
    const float* wm   = (const float*)d_in[9];
    const float* Wp   = (const float*)d_in[10];
    const float* bp   = (const float*)d_in[11];
    const float* Wd   = (const float*)d_in[12];
    const float* bd   = (const float*)d_in[13];
    float* out = (float*)d_out;
    float* ws  = (float*)d_ws;

    precompute_all<<<300, 320, 0, stream>>>(Wk, bk, Wq, bq, wm, Wp, bp, ws);
    memnet_main<<<512, 1024, 0, stream>>>(text, asp, emb, Wx, bx, Wd, bd, ws, out);
}